// Round 6
// baseline (364.290 us; speedup 1.0000x reference)
//
#include <hip/hip_runtime.h>
#include <cstdint>
#include <cstddef>

typedef unsigned short u16;
typedef __attribute__((ext_vector_type(2))) unsigned short u16x2;
typedef __attribute__((ext_vector_type(4))) unsigned short u16x4;
typedef __attribute__((ext_vector_type(8))) unsigned short u16x8;
typedef __attribute__((ext_vector_type(8))) short s16x8;
typedef __attribute__((ext_vector_type(4))) float f32x4;

// fp32 -> bf16 round-to-nearest-even
__device__ __forceinline__ u16 f2bf(float f) {
  uint32_t u = __float_as_uint(f);
  u += 0x7fffu + ((u >> 16) & 1u);
  return (u16)(u >> 16);
}

__device__ __forceinline__ f32x4 mfma16(s16x8 a, s16x8 b, f32x4 c) {
  return __builtin_amdgcn_mfma_f32_16x16x32_bf16(a, b, c, 0, 0, 0);
}

#define GLDS16(gp, lp) __builtin_amdgcn_global_load_lds(                     \
    (const __attribute__((address_space(1))) void*)(gp),                      \
    (__attribute__((address_space(3))) void*)(lp), 16, 0, 0)

// ---------------- fused fp32 -> bf16 conversion (x, Wqkv, Wproj) -----------
__global__ void cvt_all(const float* __restrict__ x, const float* __restrict__ wq,
                        const float* __restrict__ wp, u16* __restrict__ xb,
                        u16* __restrict__ wqb, u16* __restrict__ wpb) {
  const int n4x = 2097152, n4q = 786432, n4p = 262144;
  const int total = n4x + n4q + n4p;
  const int stride = gridDim.x * blockDim.x;
  for (int i = blockIdx.x * blockDim.x + threadIdx.x; i < total; i += stride) {
    const float* src;
    u16* dst;
    int j = i;
    if (j < n4x) {
      src = x; dst = xb;
    } else if (j < n4x + n4q) {
      j -= n4x; src = wq; dst = wqb;
    } else {
      j -= n4x + n4q; src = wp; dst = wpb;
    }
    f32x4 v = ((const f32x4*)src)[j];
    u16x4 o;
    o[0] = f2bf(v[0]); o[1] = f2bf(v[1]); o[2] = f2bf(v[2]); o[3] = f2bf(v[3]);
    ((u16x4*)dst)[j] = o;
  }
}

// ---------------- bf16 GEMM: C[M,N] = A[M,K] * B[N,K]^T + bias[N] ----------
// m97 structure (known-good; unchanged).
template <int OUT_BF16>
__global__ __launch_bounds__(256, 2)
void gemm_bt(const u16* __restrict__ A, const u16* __restrict__ B,
             const float* __restrict__ bias, u16* __restrict__ Cb,
             float* __restrict__ Cf, int M, int N, int K, int tilesN) {
  __shared__ u16 lA[128 * 32];
  __shared__ u16 lB[128 * 32];

  int bid = blockIdx.x;
  int cpx = gridDim.x >> 3;
  bid = (bid & 7) * cpx + (bid >> 3);

  const int tm = bid / tilesN, tn = bid % tilesN;
  const int row0 = tm * 128, col0 = tn * 128;
  const int tid = threadIdx.x;
  const int lane = tid & 63, wave = tid >> 6;

  const u16* Ag = A + (size_t)(row0 + (tid >> 2)) * K + (tid & 3) * 8;
  const u16* Bg = B + (size_t)(col0 + (tid >> 2)) * K + (tid & 3) * 8;
  const int ldsoff = tid * 8;

  const int wm = (wave >> 1) * 64, wn = (wave & 1) * 64;
  const int fr = lane & 15, fk = (lane >> 4) * 8;

  f32x4 acc[4][4] = {};

  for (int k0 = 0; k0 < K; k0 += 32) {
    __syncthreads();
    GLDS16(Ag + k0, &lA[ldsoff]);
    GLDS16(Ag + (size_t)64 * K + k0, &lA[2048 + ldsoff]);
    GLDS16(Bg + k0, &lB[ldsoff]);
    GLDS16(Bg + (size_t)64 * K + k0, &lB[2048 + ldsoff]);
    __syncthreads();

    s16x8 af[4], bfr[4];
#pragma unroll
    for (int i = 0; i < 4; ++i) af[i] = *(const s16x8*)&lA[(wm + i * 16 + fr) * 32 + fk];
#pragma unroll
    for (int i = 0; i < 4; ++i) bfr[i] = *(const s16x8*)&lB[(wn + i * 16 + fr) * 32 + fk];
#pragma unroll
    for (int i = 0; i < 4; ++i)
#pragma unroll
      for (int j = 0; j < 4; ++j) acc[i][j] = mfma16(af[i], bfr[j], acc[i][j]);
  }

#pragma unroll
  for (int i = 0; i < 4; ++i) {
#pragma unroll
    for (int r = 0; r < 4; ++r) {
      const int row = row0 + wm + i * 16 + (lane >> 4) * 4 + r;
#pragma unroll
      for (int j = 0; j < 4; ++j) {
        const int col = col0 + wn + j * 16 + fr;
        const float v = acc[i][j][r] + bias[col];
        if (OUT_BF16)
          Cb[(size_t)row * N + col] = f2bf(v);
        else
          Cf[(size_t)row * N + col] = v;
      }
    }
  }
}

// ---------------- V transpose: qkv V-section -> vt[bh][hd][kv] -------------
__global__ __launch_bounds__(256)
void vtrans(const u16* __restrict__ qkv, u16* __restrict__ vt) {
  __shared__ u16 lT[64][68];
  const int bid = blockIdx.x;
  const int bh = bid >> 4;
  const int tt = bid & 15;
  const int b = bh >> 4, h = bh & 15;
  const int tid = threadIdx.x;
  const int row = tid >> 2;
  const int cc = (tid & 3) * 16;

  const u16* src = qkv + (size_t)(b * 1024 + tt * 64 + row) * 3072 + 2048 + h * 64 + cc;
  *(u16x8*)&lT[row][cc] = *(const u16x8*)src;
  *(u16x8*)&lT[row][cc + 8] = *(const u16x8*)(src + 8);
  __syncthreads();

  u16 tmp[16];
#pragma unroll
  for (int i = 0; i < 16; ++i) tmp[i] = lT[cc + i][row];
  u16* dst = vt + (size_t)(bh * 64 + row) * 1024 + tt * 64 + cc;
  *(u16x8*)dst = *(u16x8*)&tmp[0];
  *(u16x8*)(dst + 8) = *(u16x8*)&tmp[8];
}

// ---------------- attention tile step (16 q-rows per wave) ------------------
// NF = number of 16-row kv fragments (4 -> 64 kv, 2 -> 32 kv).
// CAUSAL adds per-element kv>q mask (diagonal tile only).
// Pad mask enters as additive bias pb[kv] in {0,-3e38} (one fma).
// T13 defer-max: skip rescale when tile max stays within m+8.
template <int NF, bool CAUSAL>
__device__ __forceinline__ void attn_step5(
    const u16* __restrict__ Kbase, const u16* __restrict__ Vbase,
    const float* __restrict__ pb, u16* __restrict__ lp, int kvb, int qb,
    int fr, int grp, const s16x8 qf[2], f32x4 oacc[4], float& m2, float& l2,
    float cs) {
  // ---- S^T = K * Q^T  (C: row=kv, col=q)
  f32x4 st[NF];
#pragma unroll
  for (int f = 0; f < NF; ++f) {
    const u16* kp = Kbase + (size_t)(kvb + f * 16 + fr) * 3072 + grp * 8;
    s16x8 ka0 = *(const s16x8*)kp;
    s16x8 ka1 = *(const s16x8*)(kp + 32);
    f32x4 a = {0.f, 0.f, 0.f, 0.f};
    a = mfma16(ka0, qf[0], a);
    a = mfma16(ka1, qf[1], a);
    st[f] = a;
  }

  // ---- pad bias (broadcast LDS read)
  f32x4 pbv[NF];
#pragma unroll
  for (int f = 0; f < NF; ++f)
    pbv[f] = *(const f32x4*)&pb[kvb + f * 16 + grp * 4];

  // ---- scale+bias(+causal), tile max per q-row
  const int q = qb + fr;
  float t = -3.0e38f;
#pragma unroll
  for (int f = 0; f < NF; ++f)
#pragma unroll
    for (int r = 0; r < 4; ++r) {
      float v = __builtin_fmaf(st[f][r], cs, pbv[f][r]);
      if (CAUSAL) {
        const int kv = kvb + f * 16 + grp * 4 + r;
        v = (kv > q) ? -3.0e38f : v;
      }
      st[f][r] = v;
      t = fmaxf(t, v);
    }
  t = fmaxf(t, __shfl_xor(t, 16));
  t = fmaxf(t, __shfl_xor(t, 32));

  // ---- T13: rescale only when the max grows past THR=8
  if (!__all(t <= m2 + 8.0f)) {
    const float mn = fmaxf(m2, t);
    const float al = __expf(m2 - mn);
    m2 = mn;
    l2 *= al;
    float ar[4];
#pragma unroll
    for (int r = 0; r < 4; ++r) ar[r] = __shfl(al, grp * 4 + r);
#pragma unroll
    for (int nf = 0; nf < 4; ++nf) {
      oacc[nf][0] *= ar[0];
      oacc[nf][1] *= ar[1];
      oacc[nf][2] *= ar[2];
      oacc[nf][3] *= ar[3];
    }
  }

  // ---- P = exp(v - m), pack bf16 pairs via v_perm, accumulate l
  float rsum = 0.f;
#pragma unroll
  for (int f = 0; f < NF; ++f)
#pragma unroll
    for (int rp = 0; rp < 2; ++rp) {
      const float p0 = __expf(st[f][2 * rp] - m2);
      const float p1 = __expf(st[f][2 * rp + 1] - m2);
      rsum += p0 + p1;
      const uint32_t pk = __builtin_amdgcn_perm(
          __float_as_uint(p1) + 0x8000u, __float_as_uint(p0) + 0x8000u,
          0x07060302u);
      *(uint32_t*)&lp[fr * 72 + f * 16 + grp * 4 + 2 * rp] = pk;
    }
  rsum += __shfl_xor(rsum, 16);
  rsum += __shfl_xor(rsum, 32);
  l2 += rsum;

  // ---- PV
  s16x8 pa[NF / 2];
#pragma unroll
  for (int kc = 0; kc < NF / 2; ++kc)
    pa[kc] = *(const s16x8*)&lp[fr * 72 + kc * 32 + grp * 8];
#pragma unroll
  for (int nf = 0; nf < 4; ++nf) {
    const u16* vp = Vbase + (size_t)(nf * 16 + fr) * 1024 + kvb + grp * 8;
    s16x8 vb0 = *(const s16x8*)vp;
    f32x4 o = oacc[nf];
    o = mfma16(pa[0], vb0, o);
    if (NF == 4) o = mfma16(pa[1], *(const s16x8*)(vp + 32), o);
    oacc[nf] = o;
  }
}

// ---------------- causal flash attention v5: 16 q-rows/wave, 64-VGPR -------
__global__ __launch_bounds__(256, 8)
void attn5(const u16* __restrict__ qkv, const u16* __restrict__ vt,
           const unsigned char* __restrict__ pmask,
           const float* __restrict__ scale_ptr, u16* __restrict__ outp) {
  __shared__ u16 lP[4][16 * 72];  // per-wave P round-trip
  __shared__ float lPb[1024];     // pad bias for this b
  const int tid = threadIdx.x;
  const int lane = tid & 63, wave = tid >> 6;
  const int fr = lane & 15, grp = lane >> 4;
  const int w = blockIdx.x * 4 + wave;
  const int qi = 63 - (w >> 7);  // longest-first; uniform per block
  const int bh = w & 127;        // b uniform per block (4-wave range < 16)
  const int b = bh >> 4, h = bh & 15;
  const int qb = qi * 16;
  const float cs = scale_ptr[0];

  for (int i = tid; i < 1024; i += 256)
    lPb[i] = pmask[b * 1024 + i] ? -3.0e38f : 0.0f;
  __syncthreads();

  const u16* Kbase = qkv + (size_t)b * 1024 * 3072 + 1024 + h * 64;
  const u16* Vbase = vt + (size_t)bh * 64 * 1024;
  u16* lp = &lP[wave][0];

  // Q fragments (B-operand): col=q=fr, k=c*32+grp*8+j
  s16x8 qf[2];
#pragma unroll
  for (int c = 0; c < 2; ++c)
    qf[c] = *(const s16x8*)(qkv + (size_t)(b * 1024 + qb + fr) * 3072 +
                            h * 64 + c * 32 + grp * 8);

  f32x4 oacc[4] = {};
  float m2 = -1e30f, l2 = 0.0f;

  // noncausal 32-units: n = qi>>1; then one causal 32-unit at kvb = n*32
  const int n = qi >> 1;
  int u = 0;
  for (; u + 2 <= n; u += 2)
    attn_step5<4, false>(Kbase, Vbase, lPb, lp, u * 32, qb, fr, grp, qf, oacc, m2, l2, cs);
  if (u < n)
    attn_step5<2, false>(Kbase, Vbase, lPb, lp, u * 32, qb, fr, grp, qf, oacc, m2, l2, cs);
  attn_step5<2, true>(Kbase, Vbase, lPb, lp, n * 32, qb, fr, grp, qf, oacc, m2, l2, cs);

  // ---- epilogue: q = qb+grp*4+r, hd = nf*16+fr
  float linv[4];
#pragma unroll
  for (int r = 0; r < 4; ++r) linv[r] = 1.0f / __shfl(l2, grp * 4 + r);
#pragma unroll
  for (int nf = 0; nf < 4; ++nf)
#pragma unroll
    for (int r = 0; r < 4; ++r) {
      const int tq = qb + grp * 4 + r;
      outp[(size_t)(b * 1024 + tq) * 1024 + h * 64 + nf * 16 + fr] =
          f2bf(oacc[nf][r] * linv[r]);
    }
}

// ---------------- launch ----------------------------------------------------
extern "C" void kernel_launch(void* const* d_in, const int* in_sizes, int n_in,
                              void* d_out, int out_size, void* d_ws, size_t ws_size,
                              hipStream_t stream) {
  const float* x = (const float*)d_in[0];
  const unsigned char* pmask = (const unsigned char*)d_in[1];
  const float* Wqkv = (const float*)d_in[2];
  const float* bqkv = (const float*)d_in[3];
  const float* Wproj = (const float*)d_in[4];
  const float* bproj = (const float*)d_in[5];
  const float* scale = (const float*)d_in[6];
  float* out = (float*)d_out;

  char* ws = (char*)d_ws;
  u16* xb     = (u16*)(ws + 0);          // 16 MB; dead after gemm1
  u16* vtb    = (u16*)(ws + 0);          // aliases xb: vt[bh][hd][kv]
  u16* wqkvb  = (u16*)(ws + 16777216);   // 6 MB
  u16* wprojb = (u16*)(ws + 23068672);   // 2 MB
  u16* qkv    = (u16*)(ws + 25165824);   // 48 MB
  u16* attno  = (u16*)(ws + 75497472);   // 16 MB
  if (ws_size < (size_t)92274688) return;

  cvt_all<<<2048, 256, 0, stream>>>(x, Wqkv, Wproj, xb, wqkvb, wprojb);

  // QKV = x @ Wqkv^T + b : [8192, 3072] bf16
  gemm_bt<1><<<64 * 24, 256, 0, stream>>>(xb, wqkvb, bqkv, qkv, nullptr,
                                          8192, 3072, 1024, 24);
  // V -> vt[bh][hd][kv]
  vtrans<<<2048, 256, 0, stream>>>(qkv, vtb);
  // attention: 2048 blocks x 4 waves, 16 q-rows per wave
  attn5<<<2048, 256, 0, stream>>>(qkv, vtb, pmask, scale, attno);
  // out = attno @ Wproj^T + b : [8192, 1024] fp32
  gemm_bt<0><<<64 * 8, 256, 0, stream>>>(attno, wprojb, bproj, nullptr, out,
                                         8192, 1024, 1024, 8);
}

// Round 7
// 296.317 us; speedup vs baseline: 1.2294x; 1.2294x over previous
//
#include <hip/hip_runtime.h>
#include <cstdint>
#include <cstddef>

typedef unsigned short u16;
typedef __attribute__((ext_vector_type(2))) unsigned short u16x2;
typedef __attribute__((ext_vector_type(4))) unsigned short u16x4;
typedef __attribute__((ext_vector_type(8))) unsigned short u16x8;
typedef __attribute__((ext_vector_type(8))) short s16x8;
typedef __attribute__((ext_vector_type(4))) float f32x4;

// fp32 -> bf16 round-to-nearest-even
__device__ __forceinline__ u16 f2bf(float f) {
  uint32_t u = __float_as_uint(f);
  u += 0x7fffu + ((u >> 16) & 1u);
  return (u16)(u >> 16);
}

__device__ __forceinline__ f32x4 mfma16(s16x8 a, s16x8 b, f32x4 c) {
  return __builtin_amdgcn_mfma_f32_16x16x32_bf16(a, b, c, 0, 0, 0);
}

#define GLDS16(gp, lp) __builtin_amdgcn_global_load_lds(                     \
    (const __attribute__((address_space(1))) void*)(gp),                      \
    (__attribute__((address_space(3))) void*)(lp), 16, 0, 0)

// ---------------- fused fp32 -> bf16 conversion (x, Wqkv, Wproj) -----------
__global__ void cvt_all(const float* __restrict__ x, const float* __restrict__ wq,
                        const float* __restrict__ wp, u16* __restrict__ xb,
                        u16* __restrict__ wqb, u16* __restrict__ wpb) {
  const int n4x = 2097152, n4q = 786432, n4p = 262144;
  const int total = n4x + n4q + n4p;
  const int stride = gridDim.x * blockDim.x;
  for (int i = blockIdx.x * blockDim.x + threadIdx.x; i < total; i += stride) {
    const float* src;
    u16* dst;
    int j = i;
    if (j < n4x) {
      src = x; dst = xb;
    } else if (j < n4x + n4q) {
      j -= n4x; src = wq; dst = wqb;
    } else {
      j -= n4x + n4q; src = wp; dst = wpb;
    }
    f32x4 v = ((const f32x4*)src)[j];
    u16x4 o;
    o[0] = f2bf(v[0]); o[1] = f2bf(v[1]); o[2] = f2bf(v[2]); o[3] = f2bf(v[3]);
    ((u16x4*)dst)[j] = o;
  }
}

// ---------------- bf16 GEMM: C[M,N] = A[M,K] * B[N,K]^T + bias[N] ----------
// m97 structure (known-good; unchanged).
template <int OUT_BF16>
__global__ __launch_bounds__(256, 2)
void gemm_bt(const u16* __restrict__ A, const u16* __restrict__ B,
             const float* __restrict__ bias, u16* __restrict__ Cb,
             float* __restrict__ Cf, int M, int N, int K, int tilesN) {
  __shared__ u16 lA[128 * 32];
  __shared__ u16 lB[128 * 32];

  int bid = blockIdx.x;
  int cpx = gridDim.x >> 3;
  bid = (bid & 7) * cpx + (bid >> 3);

  const int tm = bid / tilesN, tn = bid % tilesN;
  const int row0 = tm * 128, col0 = tn * 128;
  const int tid = threadIdx.x;
  const int lane = tid & 63, wave = tid >> 6;

  const u16* Ag = A + (size_t)(row0 + (tid >> 2)) * K + (tid & 3) * 8;
  const u16* Bg = B + (size_t)(col0 + (tid >> 2)) * K + (tid & 3) * 8;
  const int ldsoff = tid * 8;

  const int wm = (wave >> 1) * 64, wn = (wave & 1) * 64;
  const int fr = lane & 15, fk = (lane >> 4) * 8;

  f32x4 acc[4][4] = {};

  for (int k0 = 0; k0 < K; k0 += 32) {
    __syncthreads();
    GLDS16(Ag + k0, &lA[ldsoff]);
    GLDS16(Ag + (size_t)64 * K + k0, &lA[2048 + ldsoff]);
    GLDS16(Bg + k0, &lB[ldsoff]);
    GLDS16(Bg + (size_t)64 * K + k0, &lB[2048 + ldsoff]);
    __syncthreads();

    s16x8 af[4], bfr[4];
#pragma unroll
    for (int i = 0; i < 4; ++i) af[i] = *(const s16x8*)&lA[(wm + i * 16 + fr) * 32 + fk];
#pragma unroll
    for (int i = 0; i < 4; ++i) bfr[i] = *(const s16x8*)&lB[(wn + i * 16 + fr) * 32 + fk];
#pragma unroll
    for (int i = 0; i < 4; ++i)
#pragma unroll
      for (int j = 0; j < 4; ++j) acc[i][j] = mfma16(af[i], bfr[j], acc[i][j]);
  }

#pragma unroll
  for (int i = 0; i < 4; ++i) {
#pragma unroll
    for (int r = 0; r < 4; ++r) {
      const int row = row0 + wm + i * 16 + (lane >> 4) * 4 + r;
#pragma unroll
      for (int j = 0; j < 4; ++j) {
        const int col = col0 + wn + j * 16 + fr;
        const float v = acc[i][j][r] + bias[col];
        if (OUT_BF16)
          Cb[(size_t)row * N + col] = f2bf(v);
        else
          Cf[(size_t)row * N + col] = v;
      }
    }
  }
}

// ---------------- V transpose: qkv V-section -> vt[bh][hd][kv] -------------
__global__ __launch_bounds__(256)
void vtrans(const u16* __restrict__ qkv, u16* __restrict__ vt) {
  __shared__ u16 lT[64][68];
  const int bid = blockIdx.x;
  const int bh = bid >> 4;
  const int tt = bid & 15;
  const int b = bh >> 4, h = bh & 15;
  const int tid = threadIdx.x;
  const int row = tid >> 2;
  const int cc = (tid & 3) * 16;

  const u16* src = qkv + (size_t)(b * 1024 + tt * 64 + row) * 3072 + 2048 + h * 64 + cc;
  *(u16x8*)&lT[row][cc] = *(const u16x8*)src;
  *(u16x8*)&lT[row][cc + 8] = *(const u16x8*)(src + 8);
  __syncthreads();

  u16 tmp[16];
#pragma unroll
  for (int i = 0; i < 16; ++i) tmp[i] = lT[cc + i][row];
  u16* dst = vt + (size_t)(bh * 64 + row) * 1024 + tt * 64 + cc;
  *(u16x8*)dst = *(u16x8*)&tmp[0];
  *(u16x8*)(dst + 8) = *(u16x8*)&tmp[8];
}

// ---------------- attention tile step, complementary-pair version ----------
// Wave owns TWO 16-row q-chunks: g=0 (low, base qblo) and g=1 (high, qbhi).
// NF = 16-row kv fragments in this step (4 -> 64 kv, 2 -> 32 kv).
// LO/HI: chunk active this step. CLO/CHI: apply causal mask for that chunk.
// K/V fragments are loaded once and shared by both active chunks.
template <int NF, bool LO, bool HI, bool CLO, bool CHI>
__device__ __forceinline__ void attn_step6(
    const u16* __restrict__ Kbase, const u16* __restrict__ Vbase,
    const float* __restrict__ pb, u16* __restrict__ lp, int kvb, int qblo,
    int qbhi, int fr, int grp, const s16x8 qf[2][2], f32x4 oacc[2][4],
    float m2[2], float l2[2], float cs) {
  // ---- S^T = K * Q^T  (C: row=kv, col=q)
  f32x4 st[NF][2];
#pragma unroll
  for (int f = 0; f < NF; ++f) {
    const u16* kp = Kbase + (size_t)(kvb + f * 16 + fr) * 3072 + grp * 8;
    s16x8 ka0 = *(const s16x8*)kp;
    s16x8 ka1 = *(const s16x8*)(kp + 32);
    if (LO) {
      f32x4 a = {0.f, 0.f, 0.f, 0.f};
      a = mfma16(ka0, qf[0][0], a);
      a = mfma16(ka1, qf[0][1], a);
      st[f][0] = a;
    }
    if (HI) {
      f32x4 a = {0.f, 0.f, 0.f, 0.f};
      a = mfma16(ka0, qf[1][0], a);
      a = mfma16(ka1, qf[1][1], a);
      st[f][1] = a;
    }
  }

  // ---- pad bias (broadcast LDS read, shared across chunks)
  f32x4 pbv[NF];
#pragma unroll
  for (int f = 0; f < NF; ++f)
    pbv[f] = *(const f32x4*)&pb[kvb + f * 16 + grp * 4];

  // ---- per-chunk softmax
#pragma unroll
  for (int g = 0; g < 2; ++g) {
    if ((g == 0 && !LO) || (g == 1 && !HI)) continue;
    const bool CG = (g == 0) ? CLO : CHI;
    const int q = ((g == 0) ? qblo : qbhi) + fr;
    float t = -3.0e38f;
#pragma unroll
    for (int f = 0; f < NF; ++f)
#pragma unroll
      for (int r = 0; r < 4; ++r) {
        float v = __builtin_fmaf(st[f][g][r], cs, pbv[f][r]);
        if (CG) {
          const int kv = kvb + f * 16 + grp * 4 + r;
          v = (kv > q) ? -3.0e38f : v;
        }
        st[f][g][r] = v;
        t = fmaxf(t, v);
      }
    t = fmaxf(t, __shfl_xor(t, 16));
    t = fmaxf(t, __shfl_xor(t, 32));

    // T13 defer-max: rescale only when the max grows past THR=8
    if (!__all(t <= m2[g] + 8.0f)) {
      const float mn = fmaxf(m2[g], t);
      const float al = __expf(m2[g] - mn);
      m2[g] = mn;
      l2[g] *= al;
      float ar[4];
#pragma unroll
      for (int r = 0; r < 4; ++r) ar[r] = __shfl(al, grp * 4 + r);
#pragma unroll
      for (int nf = 0; nf < 4; ++nf) {
        oacc[g][nf][0] *= ar[0];
        oacc[g][nf][1] *= ar[1];
        oacc[g][nf][2] *= ar[2];
        oacc[g][nf][3] *= ar[3];
      }
    }

    // P = exp(v - m), pack bf16 pairs via v_perm, accumulate l
    float rsum = 0.f;
#pragma unroll
    for (int f = 0; f < NF; ++f)
#pragma unroll
      for (int rp = 0; rp < 2; ++rp) {
        const float p0 = __expf(st[f][g][2 * rp] - m2[g]);
        const float p1 = __expf(st[f][g][2 * rp + 1] - m2[g]);
        rsum += p0 + p1;
        const uint32_t pk = __builtin_amdgcn_perm(
            __float_as_uint(p1) + 0x8000u, __float_as_uint(p0) + 0x8000u,
            0x07060302u);
        *(uint32_t*)&lp[(g * 16 + fr) * 72 + f * 16 + grp * 4 + 2 * rp] = pk;
      }
    rsum += __shfl_xor(rsum, 16);
    rsum += __shfl_xor(rsum, 32);
    l2[g] += rsum;
  }

  // ---- PV (V fragments shared by both active chunks)
  s16x8 pa[2][NF / 2];
#pragma unroll
  for (int g = 0; g < 2; ++g) {
    if ((g == 0 && !LO) || (g == 1 && !HI)) continue;
#pragma unroll
    for (int kc = 0; kc < NF / 2; ++kc)
      pa[g][kc] = *(const s16x8*)&lp[(g * 16 + fr) * 72 + kc * 32 + grp * 8];
  }
#pragma unroll
  for (int nf = 0; nf < 4; ++nf) {
    const u16* vp = Vbase + (size_t)(nf * 16 + fr) * 1024 + kvb + grp * 8;
    s16x8 vb0 = *(const s16x8*)vp;
    s16x8 vb1;
    if (NF == 4) vb1 = *(const s16x8*)(vp + 32);
#pragma unroll
    for (int g = 0; g < 2; ++g) {
      if ((g == 0 && !LO) || (g == 1 && !HI)) continue;
      f32x4 o = oacc[g][nf];
      o = mfma16(pa[g][0], vb0, o);
      if (NF == 4) o = mfma16(pa[g][1], vb1, o);
      oacc[g][nf] = o;
    }
  }
}

// ---------------- causal flash attention v6: balanced complementary pairs --
// Wave w handles q-chunks p and 63-p (16 rows each) of one (b,h):
// per-wave MFMA work is ~constant (65*16 kv-rows), eliminating the causal
// imbalance tail. K/V frags shared over the common kv range; low chunk is
// compile-time disabled past its diagonal.
__global__ __launch_bounds__(256, 4)
void attn6(const u16* __restrict__ qkv, const u16* __restrict__ vt,
           const unsigned char* __restrict__ pmask,
           const float* __restrict__ scale_ptr, u16* __restrict__ outp) {
  __shared__ u16 lP[4][32 * 72];
  __shared__ float lPb[1024];
  const int tid = threadIdx.x;
  const int lane = tid & 63, wave = tid >> 6;
  const int fr = lane & 15, grp = lane >> 4;
  const int bid = blockIdx.x;
  const int bh = bid & 127;  // b uniform per block
  const int b = bh >> 4, h = bh & 15;
  const int p = (bid >> 7) * 4 + wave;  // 0..31
  const int qblo = p * 16;
  const int qbhi = (63 - p) * 16;
  const float cs = scale_ptr[0];

  for (int i = tid; i < 1024; i += 256)
    lPb[i] = pmask[b * 1024 + i] ? -3.0e38f : 0.0f;
  __syncthreads();

  const u16* Kbase = qkv + (size_t)b * 1024 * 3072 + 1024 + h * 64;
  const u16* Vbase = vt + (size_t)bh * 64 * 1024;
  u16* lp = &lP[wave][0];

  // Q fragments (B-operand): col = q = qb[g]+fr, k = c*32+grp*8+j
  s16x8 qf[2][2];
#pragma unroll
  for (int g = 0; g < 2; ++g) {
    const int qb = g ? qbhi : qblo;
#pragma unroll
    for (int c = 0; c < 2; ++c)
      qf[g][c] = *(const s16x8*)(qkv + (size_t)(b * 1024 + qb + fr) * 3072 +
                                 h * 64 + c * 32 + grp * 8);
  }

  f32x4 oacc[2][4] = {};
  float m2[2] = {-1e30f, -1e30f};
  float l2[2] = {0.0f, 0.0f};

  const int nlo = (p >> 1) + 1;         // 32-kv units incl. low diagonal
  const int nhi = ((63 - p) >> 1) + 1;  // 32-kv units incl. high diagonal

  // Phase A: strictly below low diagonal — both chunks, noncausal
  int u = 0;
  for (; u + 2 <= nlo - 1; u += 2)
    attn_step6<4, true, true, false, false>(Kbase, Vbase, lPb, lp, u * 32,
                                            qblo, qbhi, fr, grp, qf, oacc, m2, l2, cs);
  if (u < nlo - 1) {
    attn_step6<2, true, true, false, false>(Kbase, Vbase, lPb, lp, u * 32,
                                            qblo, qbhi, fr, grp, qf, oacc, m2, l2, cs);
    ++u;
  }
  // Phase B: low diagonal unit — low causal, high noncausal
  attn_step6<2, true, true, true, false>(Kbase, Vbase, lPb, lp, (nlo - 1) * 32,
                                         qblo, qbhi, fr, grp, qf, oacc, m2, l2, cs);
  u = nlo;
  // Phase C: between diagonals — high only, noncausal
  for (; u + 2 <= nhi - 1; u += 2)
    attn_step6<4, false, true, false, false>(Kbase, Vbase, lPb, lp, u * 32,
                                             qblo, qbhi, fr, grp, qf, oacc, m2, l2, cs);
  if (u < nhi - 1) {
    attn_step6<2, false, true, false, false>(Kbase, Vbase, lPb, lp, u * 32,
                                             qblo, qbhi, fr, grp, qf, oacc, m2, l2, cs);
    ++u;
  }
  // Phase D: high diagonal unit — high causal
  attn_step6<2, false, true, false, true>(Kbase, Vbase, lPb, lp, (nhi - 1) * 32,
                                          qblo, qbhi, fr, grp, qf, oacc, m2, l2, cs);

  // ---- epilogue: q = qb[g]+grp*4+r, hd = nf*16+fr
#pragma unroll
  for (int g = 0; g < 2; ++g) {
    const int qb = g ? qbhi : qblo;
    float linv[4];
#pragma unroll
    for (int r = 0; r < 4; ++r) linv[r] = 1.0f / __shfl(l2[g], grp * 4 + r);
#pragma unroll
    for (int nf = 0; nf < 4; ++nf)
#pragma unroll
      for (int r = 0; r < 4; ++r) {
        const int tq = qb + grp * 4 + r;
        outp[(size_t)(b * 1024 + tq) * 1024 + h * 64 + nf * 16 + fr] =
            f2bf(oacc[g][nf][r] * linv[r]);
      }
  }
}

// ---------------- launch ----------------------------------------------------
extern "C" void kernel_launch(void* const* d_in, const int* in_sizes, int n_in,
                              void* d_out, int out_size, void* d_ws, size_t ws_size,
                              hipStream_t stream) {
  const float* x = (const float*)d_in[0];
  const unsigned char* pmask = (const unsigned char*)d_in[1];
  const float* Wqkv = (const float*)d_in[2];
  const float* bqkv = (const float*)d_in[3];
  const float* Wproj = (const float*)d_in[4];
  const float* bproj = (const float*)d_in[5];
  const float* scale = (const float*)d_in[6];
  float* out = (float*)d_out;

  char* ws = (char*)d_ws;
  u16* xb     = (u16*)(ws + 0);          // 16 MB; dead after gemm1
  u16* vtb    = (u16*)(ws + 0);          // aliases xb: vt[bh][hd][kv]
  u16* wqkvb  = (u16*)(ws + 16777216);   // 6 MB
  u16* wprojb = (u16*)(ws + 23068672);   // 2 MB
  u16* qkv    = (u16*)(ws + 25165824);   // 48 MB
  u16* attno  = (u16*)(ws + 75497472);   // 16 MB
  if (ws_size < (size_t)92274688) return;

  cvt_all<<<2048, 256, 0, stream>>>(x, Wqkv, Wproj, xb, wqkvb, wprojb);

  // QKV = x @ Wqkv^T + b : [8192, 3072] bf16
  gemm_bt<1><<<64 * 24, 256, 0, stream>>>(xb, wqkvb, bqkv, qkv, nullptr,
                                          8192, 3072, 1024, 24);
  // V -> vt[bh][hd][kv]
  vtrans<<<2048, 256, 0, stream>>>(qkv, vtb);
  // attention: 1024 blocks x 4 waves; wave = complementary chunk pair
  attn6<<<1024, 256, 0, stream>>>(qkv, vtb, pmask, scale, attno);
  // out = attno @ Wproj^T + b : [8192, 1024] fp32
  gemm_bt<0><<<64 * 8, 256, 0, stream>>>(attno, wprojb, bproj, nullptr, out,
                                         8192, 1024, 1024, 8);
}